// Round 9
// baseline (229.625 us; speedup 1.0000x reference)
//
#include <hip/hip_runtime.h>

#define S_LEN 4096
#define NH 16
#define DH 64
#define NE 1024

typedef __bf16 bf16_t;
typedef __bf16 bf16x8 __attribute__((ext_vector_type(8)));
typedef __bf16 bf16x4 __attribute__((ext_vector_type(4)));
typedef __bf16 bf16x2 __attribute__((ext_vector_type(2)));
typedef float  f32x4  __attribute__((ext_vector_type(4)));

#define QSCALE 0.180336879f  // 0.125 * log2(e): softmax in exp2 domain

// ---------------------------------------------------------------------------
// Fused pack kernel (unchanged). Blocks [0,4096): q,k -> head-major bf16
// (q pre-scaled QSCALE) + W -> bf16. Blocks [4096,5120): V -> vt[h][d][t']
// transpose with the within-64 key permutation (vt[pos] = V[ip(pos)]) so
// attn's PV B-fragment is one contiguous b128. Lanes write CONTIGUOUS vt
// addresses, read inverse-permuted LDS entries.
// ---------------------------------------------------------------------------
__global__ __launch_bounds__(256) void pack_all(const float* __restrict__ q,
                                                const float* __restrict__ k,
                                                const float* __restrict__ w,
                                                const float* __restrict__ v,
                                                bf16_t* __restrict__ qb,
                                                bf16_t* __restrict__ kb,
                                                bf16_t* __restrict__ wb,
                                                bf16_t* __restrict__ vt) {
    __shared__ bf16_t tile[64][65];
    const int bid = blockIdx.x;
    if (bid < 4096) {
        const int tid = bid * 256 + threadIdx.x;
        const int e = tid * 4;
        const int s = e >> 10;
        const int c = e & (NE - 1);
        const int h = c >> 6;
        const int d = c & (DH - 1);
        const int o = (h * S_LEN + s) * DH + d;
        float4 qv = *(const float4*)(q + e);
        float4 kv = *(const float4*)(k + e);
        bf16x4 qo, ko;
        qo[0] = (bf16_t)(qv.x * QSCALE); qo[1] = (bf16_t)(qv.y * QSCALE);
        qo[2] = (bf16_t)(qv.z * QSCALE); qo[3] = (bf16_t)(qv.w * QSCALE);
        ko[0] = (bf16_t)kv.x; ko[1] = (bf16_t)kv.y; ko[2] = (bf16_t)kv.z; ko[3] = (bf16_t)kv.w;
        *(bf16x4*)(qb + o) = qo;
        *(bf16x4*)(kb + o) = ko;
        if (tid < (NE * NE / 4)) {
            float4 wv = *(const float4*)(w + tid * 4);
            bf16x4 wo;
            wo[0] = (bf16_t)wv.x; wo[1] = (bf16_t)wv.y; wo[2] = (bf16_t)wv.z; wo[3] = (bf16_t)wv.w;
            *(bf16x4*)(wb + tid * 4) = wo;
        }
    } else {
        const int vb = bid - 4096;
        const int h  = vb >> 6;
        const int t0 = (vb & 63) * 64;
        const int r  = threadIdx.x >> 6;   // 0..3
        const int cl = threadIdx.x & 63;
#pragma unroll
        for (int rep = 0; rep < 16; ++rep) {
            int i = rep * 4 + r;
            tile[cl][i] = (bf16_t)v[(t0 + i) * NE + h * DH + cl];
        }
        __syncthreads();
        const int r2  = threadIdx.x >> 5;        // 0..7
        const int cl2 = (threadIdx.x & 31) * 2;  // 0..62 even
        // inverse key permutation: old = n5*32 + n2*16 + n4*8 + n3*4 + n1n0
        const int ip = (cl2 & 32) + ((cl2 >> 2) & 1) * 16 + ((cl2 >> 4) & 1) * 8 +
                       ((cl2 >> 3) & 1) * 4 + (cl2 & 3);
#pragma unroll
        for (int rep = 0; rep < 8; ++rep) {
            int d = rep * 8 + r2;
            bf16x2 out;
            out[0] = tile[d][ip];
            out[1] = tile[d][ip + 1];
            *(bf16x2*)(vt + (h * DH + d) * S_LEN + t0 + cl2) = out;
        }
    }
}

// ---------------------------------------------------------------------------
// Flash attention v16: v15's straight-line 4-wave x 32-query body (spill-free,
// conflicts halved) with the causal-fold phases split across blockIdx.z:
// z=0 -> tiles [0, n0) for stile sA -> po slot 0; z=1 -> tiles [n0, 33) for
// stile sB -> slot 1 (round-4 partition, proven correct). Grid 1024 blocks
// x 4 waves = 4096 waves = 16 waves/CU, 4 blocks/CU (LDS 4x36864 = 147456).
// Round-4's z-split regression is now attributed to __launch_bounds__(512,8)
// crushing VGPR to 32 (scratch-spill WRITE blowup), not the split itself.
// Per-CU totals (LDS instrs, staging VALU, MFMA) identical to v15; this
// purely doubles latency-hiding depth. Epilogue stores reordered (r outer,
// db inner) so each 256B po row completes in 4 consecutive 64B stores.
// ---------------------------------------------------------------------------
__global__ __launch_bounds__(256, 4) void attn(const bf16_t* __restrict__ qb,
                                               const bf16_t* __restrict__ kb,
                                               const bf16_t* __restrict__ vt,
                                               float* __restrict__ po,
                                               float* __restrict__ ls) {
    __shared__ __align__(16) bf16_t kbuf[2][64 * 72];
    __shared__ __align__(16) bf16_t vbuf[2][64 * 72];

    const int tid  = threadIdx.x;
    const int wave = tid >> 6;        // 0..3
    const int lane = tid & 63;
    const int l15  = lane & 15;
    const int quad = lane >> 4;
    const int h = blockIdx.x;
    const int x = blockIdx.y;
    const int z = blockIdx.z;

    const int sA = x;
    const int sB = 31 - x;
    const int n0 = x + 1;            // phase0 tile count
    const int b1 = sB + 1;           // phase1 first tile -> t0 base
    const int N  = 33;

    const int jb = z ? n0 : 0;       // this block's tile range [jb, je)
    const int je = z ? N  : n0;
    const int s0 = (z ? sB : sA) * 128 + wave * 32;

    const bf16_t* __restrict__ qh = qb + h * (S_LEN * DH);
    const bf16_t* __restrict__ kh = kb + h * (S_LEN * DH);
    const bf16_t* __restrict__ vh = vt + h * (DH * S_LEN);

    const int row0 = tid >> 3;        // 0..31 (second half adds 32)
    const int tc8  = (tid & 7) * 8;   // 0..56
    const int stg  = row0 * 72 + tc8; // staging LDS offset (elements)
    const int frg  = l15 * 72 + quad * 8;  // fragment base offset (elements)

    f32x4 o_acc[2][4];
    f32x4 rs[2];                      // running row-sums via ones-MFMA
    bf16x8 qA[2][2];                  // [row-group][d-chunk]
    bf16x8 ones;
#pragma unroll
    for (int e = 0; e < 8; ++e) ones[e] = (bf16_t)1.0f;

    auto t0_of = [&](int j) { return (j < n0 ? j : b1 + (j - n0)) * 64; };

#pragma unroll
    for (int g = 0; g < 2; ++g)
#pragma unroll
        for (int dc = 0; dc < 2; ++dc)
            qA[g][dc] = *(const bf16x8*)(qh + (s0 + g * 16 + l15) * DH + dc * 32 + quad * 8);
#pragma unroll
    for (int g = 0; g < 2; ++g) {
#pragma unroll
        for (int db = 0; db < 4; ++db) o_acc[g][db] = (f32x4){0.f, 0.f, 0.f, 0.f};
        rs[g] = (f32x4){0.f, 0.f, 0.f, 0.f};
    }

    {
        const int t0 = t0_of(jb);
        bf16x8 kr0 = *(const bf16x8*)(kh + (t0 + row0) * DH + tc8);
        bf16x8 kr1 = *(const bf16x8*)(kh + (t0 + row0 + 32) * DH + tc8);
        bf16x8 vr0 = *(const bf16x8*)(vh + row0 * S_LEN + t0 + tc8);
        bf16x8 vr1 = *(const bf16x8*)(vh + (row0 + 32) * S_LEN + t0 + tc8);
        *(bf16x8*)(kbuf[jb & 1] + stg) = kr0;
        *(bf16x8*)(kbuf[jb & 1] + stg + 32 * 72) = kr1;
        *(bf16x8*)(vbuf[jb & 1] + stg) = vr0;
        *(bf16x8*)(vbuf[jb & 1] + stg + 32 * 72) = vr1;
    }
    __syncthreads();

#pragma unroll 2
    for (int j = jb; j < je; ++j) {
        const int t0 = t0_of(j);
        const bf16_t* kb_ = kbuf[j & 1];
        const bf16_t* vb_ = vbuf[j & 1];

        const bool pf = (j + 1 < je);
        int tn = 0;
        bf16x8 kr0n, kr1n, vr0n, vr1n;
        if (pf) {  // K prefetch early; V prefetch after the softmax phase
            tn = t0_of(j + 1);
            kr0n = *(const bf16x8*)(kh + (tn + row0) * DH + tc8);
            kr1n = *(const bf16x8*)(kh + (tn + row0 + 32) * DH + tc8);
        }

        // wave-uniform: tile contributes only if some key <= some query
        if (t0 <= s0 + 31) {
            const bool edge = (t0 + 63 > s0);  // wave-uniform; covers all masking
            bf16x8 pA[2][2];

            // ---- swapped QK^T + softmax, one ch-pair (=one kc) at a time
#pragma unroll
            for (int kc = 0; kc < 2; ++kc) {
                const int chA = kc * 2;
                bf16x8 kB00 = *(const bf16x8*)(kb_ + frg + (chA + 0) * (16 * 72));
                bf16x8 kB01 = *(const bf16x8*)(kb_ + frg + (chA + 0) * (16 * 72) + 32);
                bf16x8 kB10 = *(const bf16x8*)(kb_ + frg + (chA + 1) * (16 * 72));
                bf16x8 kB11 = *(const bf16x8*)(kb_ + frg + (chA + 1) * (16 * 72) + 32);
                f32x4 cA[2], cB[2];
#pragma unroll
                for (int g = 0; g < 2; ++g) {
                    f32x4 zv = (f32x4){0.f, 0.f, 0.f, 0.f};
                    zv = __builtin_amdgcn_mfma_f32_16x16x32_bf16(kB00, qA[g][0], zv, 0, 0, 0);
                    zv = __builtin_amdgcn_mfma_f32_16x16x32_bf16(kB01, qA[g][1], zv, 0, 0, 0);
                    cA[g] = zv;
                    zv = (f32x4){0.f, 0.f, 0.f, 0.f};
                    zv = __builtin_amdgcn_mfma_f32_16x16x32_bf16(kB10, qA[g][0], zv, 0, 0, 0);
                    zv = __builtin_amdgcn_mfma_f32_16x16x32_bf16(kB11, qA[g][1], zv, 0, 0, 0);
                    cB[g] = zv;
                }
                // lane holds S^T[key=t0+16ch+4quad+r][query=s0+g*16+l15];
                // mask -> -inf -> exp2=0 also zeroes dead chunks exactly.
#pragma unroll
                for (int g = 0; g < 2; ++g) {
                    const int query = s0 + g * 16 + l15;
#pragma unroll
                    for (int r = 0; r < 4; ++r) {
                        float a = cA[g][r];
                        float b = cB[g][r];
                        if (edge) {
                            const int keyA = t0 + chA * 16 + quad * 4 + r;
                            if (keyA > query)      a = -INFINITY;
                            if (keyA + 16 > query) b = -INFINITY;
                        }
                        pA[g][kc][r]     = (bf16_t)exp2f(a);
                        pA[g][kc][4 + r] = (bf16_t)exp2f(b);
                    }
                }
            }

            // ---- row-sums on the matrix pipe (unconditional)
#pragma unroll
            for (int g = 0; g < 2; ++g) {
                rs[g] = __builtin_amdgcn_mfma_f32_16x16x32_bf16(pA[g][0], ones, rs[g], 0, 0, 0);
                rs[g] = __builtin_amdgcn_mfma_f32_16x16x32_bf16(pA[g][1], ones, rs[g], 0, 0, 0);
            }

            // ---- V prefetch now (PV phase covers its L2 latency)
            if (pf) {
                vr0n = *(const bf16x8*)(vh + row0 * S_LEN + tn + tc8);
                vr1n = *(const bf16x8*)(vh + (row0 + 32) * S_LEN + tn + tc8);
            }

            // ---- PV: V fragments read ONCE per wave, shared across groups
#pragma unroll
            for (int db = 0; db < 4; ++db) {
                bf16x8 vB0 = *(const bf16x8*)(vb_ + frg + db * (16 * 72));
                bf16x8 vB1 = *(const bf16x8*)(vb_ + frg + db * (16 * 72) + 32);
#pragma unroll
                for (int g = 0; g < 2; ++g) {
                    o_acc[g][db] = __builtin_amdgcn_mfma_f32_16x16x32_bf16(pA[g][0], vB0, o_acc[g][db], 0, 0, 0);
                    o_acc[g][db] = __builtin_amdgcn_mfma_f32_16x16x32_bf16(pA[g][1], vB1, o_acc[g][db], 0, 0, 0);
                }
            }
        } else if (pf) {
            vr0n = *(const bf16x8*)(vh + row0 * S_LEN + tn + tc8);
            vr1n = *(const bf16x8*)(vh + (row0 + 32) * S_LEN + tn + tc8);
        }

        if (pf) {
            bf16_t* kd = kbuf[(j + 1) & 1];
            bf16_t* vd = vbuf[(j + 1) & 1];
            *(bf16x8*)(kd + stg) = kr0n;
            *(bf16x8*)(kd + stg + 32 * 72) = kr1n;
            *(bf16x8*)(vd + stg) = vr0n;
            *(bf16x8*)(vd + stg + 32 * 72) = vr1n;
        }
        __syncthreads();
    }

    // epilogue: slot = z; r outer / db inner so each 256B row is completed
    // by 4 consecutive 64B stores (full-line writeback friendly)
    {
        float* poz = po + (size_t)(z * NH + h) * S_LEN * DH;
#pragma unroll
        for (int g = 0; g < 2; ++g)
#pragma unroll
            for (int r = 0; r < 4; ++r)
#pragma unroll
                for (int db = 0; db < 4; ++db)
                    poz[(s0 + g * 16 + quad * 4 + r) * DH + db * 16 + l15] = o_acc[g][db][r];
        if (l15 == 0) {
            float* lsz = ls + (size_t)(z * NH + h) * S_LEN;
#pragma unroll
            for (int g = 0; g < 2; ++g)
#pragma unroll
                for (int r = 0; r < 4; ++r) lsz[s0 + g * 16 + quad * 4 + r] = rs[g][r];
        }
    }
}

// ---------------------------------------------------------------------------
// Combine (unchanged): xb[row][h*64+d] = (o0 + o1) / (l0 + l1).
// ---------------------------------------------------------------------------
__global__ __launch_bounds__(256) void combine(const float* __restrict__ po,
                                               const float* __restrict__ ls,
                                               bf16_t* __restrict__ xb) {
    const int idx = blockIdx.x * 256 + threadIdx.x;
    const int row = idx >> 8;
    const int c   = (idx & 255) * 4;
    const int h   = c >> 6;
    const int d   = c & 63;
    const size_t base0 = (size_t)(h) * S_LEN * DH + row * DH + d;
    const size_t base1 = (size_t)(NH + h) * S_LEN * DH + row * DH + d;
    float4 o0 = *(const float4*)(po + base0);
    float4 o1 = *(const float4*)(po + base1);
    float l = ls[(size_t)h * S_LEN + row] + ls[(size_t)(NH + h) * S_LEN + row];
    float inv = 1.0f / l;
    bf16x4 out;
    out[0] = (bf16_t)((o0.x + o1.x) * inv);
    out[1] = (bf16_t)((o0.y + o1.y) * inv);
    out[2] = (bf16_t)((o0.z + o1.z) * inv);
    out[3] = (bf16_t)((o0.w + o1.w) * inv);
    *(bf16x4*)(xb + (size_t)row * NE + c) = out;
}

// ---------------------------------------------------------------------------
// Projection (round-5 m32 version, unchanged): Y = X(bf16) @ W^T(bf16).
// ---------------------------------------------------------------------------
__global__ __launch_bounds__(256, 4) void proj(const bf16_t* __restrict__ xb,
                                               const bf16_t* __restrict__ wb,
                                               float* __restrict__ y) {
    __shared__ __align__(16) bf16_t wbuf[2][64 * 72];
    const int tid  = threadIdx.x;
    const int wave = tid >> 6;
    const int lane = tid & 63;
    const int l15  = lane & 15;
    const int quad = lane >> 4;
    const int m0 = blockIdx.x * 128 + wave * 32;   // wave owns 32 rows
    const int n0 = blockIdx.y * 64;

    const int row0 = tid >> 3;        // 0..31 (second chunk adds 32)
    const int tc8  = (tid & 7) * 8;

    f32x4 acc[2][4];
#pragma unroll
    for (int g = 0; g < 2; ++g)
#pragma unroll
        for (int nb = 0; nb < 4; ++nb) acc[g][nb] = (f32x4){0.f, 0.f, 0.f, 0.f};

    {
        bf16x8 wr0 = *(const bf16x8*)(wb + (n0 + row0) * NE + tc8);
        bf16x8 wr1 = *(const bf16x8*)(wb + (n0 + row0 + 32) * NE + tc8);
        *(bf16x8*)(wbuf[0] + row0 * 72 + tc8) = wr0;
        *(bf16x8*)(wbuf[0] + (row0 + 32) * 72 + tc8) = wr1;
    }
    bf16x8 a[2][2];
#pragma unroll
    for (int g = 0; g < 2; ++g)
#pragma unroll
        for (int kc = 0; kc < 2; ++kc)
            a[g][kc] = *(const bf16x8*)(xb + (m0 + g * 16 + l15) * NE + kc * 32 + quad * 8);
    __syncthreads();

    for (int kt = 0; kt < 16; ++kt) {
        const bf16_t* wb_ = wbuf[kt & 1];
        const bool pf = (kt + 1 < 16);
        bf16x8 wr0, wr1, an[2][2];
        if (pf) {
            const int kn = (kt + 1) * 64;
            wr0 = *(const bf16x8*)(wb + (n0 + row0) * NE + kn + tc8);
            wr1 = *(const bf16x8*)(wb + (n0 + row0 + 32) * NE + kn + tc8);
#pragma unroll
            for (int g = 0; g < 2; ++g)
#pragma unroll
                for (int kc = 0; kc < 2; ++kc)
                    an[g][kc] = *(const bf16x8*)(xb + (m0 + g * 16 + l15) * NE + kn + kc * 32 + quad * 8);
        }

#pragma unroll
        for (int nb = 0; nb < 4; ++nb)
#pragma unroll
            for (int kc = 0; kc < 2; ++kc) {
                bf16x8 b = *(const bf16x8*)(wb_ + (nb * 16 + l15) * 72 + kc * 32 + quad * 8);
#pragma unroll
                for (int g = 0; g < 2; ++g)
                    acc[g][nb] = __builtin_amdgcn_mfma_f32_16x16x32_bf16(a[g][kc], b, acc[g][nb], 0, 0, 0);
            }

        if (pf) {
            *(bf16x8*)(wbuf[(kt + 1) & 1] + row0 * 72 + tc8) = wr0;
            *(bf16x8*)(wbuf[(kt + 1) & 1] + (row0 + 32) * 72 + tc8) = wr1;
#pragma unroll
            for (int g = 0; g < 2; ++g)
#pragma unroll
                for (int kc = 0; kc < 2; ++kc) a[g][kc] = an[g][kc];
        }
        __syncthreads();
    }

#pragma unroll
    for (int g = 0; g < 2; ++g)
#pragma unroll
        for (int nb = 0; nb < 4; ++nb)
#pragma unroll
            for (int r = 0; r < 4; ++r)
                y[(m0 + g * 16 + quad * 4 + r) * NE + n0 + nb * 16 + l15] = acc[g][nb][r];
}

extern "C" void kernel_launch(void* const* d_in, const int* in_sizes, int n_in,
                              void* d_out, int out_size, void* d_ws, size_t ws_size,
                              hipStream_t stream) {
    const float* q = (const float*)d_in[0];
    const float* k = (const float*)d_in[1];
    const float* v = (const float*)d_in[2];
    const float* w = (const float*)d_in[3];
    float* y = (float*)d_out;

    // ws: bf16 {qb 4M | kb 4M | vt 4M | wb 1M | xb 4M} then fp32 {po 8M | ls 128K}
    bf16_t* ws = (bf16_t*)d_ws;
    bf16_t* qb = ws;
    bf16_t* kb = qb + 4 * 1024 * 1024;
    bf16_t* vt = kb + 4 * 1024 * 1024;
    bf16_t* wb = vt + 4 * 1024 * 1024;
    bf16_t* xb = wb + 1024 * 1024;
    float*  po = (float*)(xb + 4 * 1024 * 1024);
    float*  ls = po + (size_t)2 * NH * S_LEN * DH;

    pack_all<<<dim3(4096 + 1024), dim3(256), 0, stream>>>(q, k, w, v, qb, kb, wb, vt);
    attn<<<dim3(NH, 32, 2), dim3(256), 0, stream>>>(qb, kb, vt, po, ls);
    combine<<<dim3(4096), dim3(256), 0, stream>>>(po, ls, xb);
    proj<<<dim3(S_LEN / 128, NE / 64), dim3(256), 0, stream>>>(xb, wb, y);
}

// Round 10
// 195.320 us; speedup vs baseline: 1.1756x; 1.1756x over previous
//
#include <hip/hip_runtime.h>

#define S_LEN 4096
#define NH 16
#define DH 64
#define NE 1024

typedef __bf16 bf16_t;
typedef __bf16 bf16x8 __attribute__((ext_vector_type(8)));
typedef __bf16 bf16x4 __attribute__((ext_vector_type(4)));
typedef __bf16 bf16x2 __attribute__((ext_vector_type(2)));
typedef float  f32x4  __attribute__((ext_vector_type(4)));

#define QSCALE 0.180336879f  // 0.125 * log2(e): softmax in exp2 domain

// ---------------------------------------------------------------------------
// Fused pack kernel (round-5 version, unchanged). Blocks [0,4096): q,k ->
// head-major bf16 (q pre-scaled QSCALE) + W -> bf16. Blocks [4096,5120):
// V -> vt[h][d][t'] transpose with the within-64 key permutation
// (vt[pos] = V[ip(pos)]) so attn's PV B-fragment is one contiguous b128.
// Lanes write CONTIGUOUS vt addresses, read inverse-permuted LDS entries.
// ---------------------------------------------------------------------------
__global__ __launch_bounds__(256) void pack_all(const float* __restrict__ q,
                                                const float* __restrict__ k,
                                                const float* __restrict__ w,
                                                const float* __restrict__ v,
                                                bf16_t* __restrict__ qb,
                                                bf16_t* __restrict__ kb,
                                                bf16_t* __restrict__ wb,
                                                bf16_t* __restrict__ vt) {
    __shared__ bf16_t tile[64][65];
    const int bid = blockIdx.x;
    if (bid < 4096) {
        const int tid = bid * 256 + threadIdx.x;
        const int e = tid * 4;
        const int s = e >> 10;
        const int c = e & (NE - 1);
        const int h = c >> 6;
        const int d = c & (DH - 1);
        const int o = (h * S_LEN + s) * DH + d;
        float4 qv = *(const float4*)(q + e);
        float4 kv = *(const float4*)(k + e);
        bf16x4 qo, ko;
        qo[0] = (bf16_t)(qv.x * QSCALE); qo[1] = (bf16_t)(qv.y * QSCALE);
        qo[2] = (bf16_t)(qv.z * QSCALE); qo[3] = (bf16_t)(qv.w * QSCALE);
        ko[0] = (bf16_t)kv.x; ko[1] = (bf16_t)kv.y; ko[2] = (bf16_t)kv.z; ko[3] = (bf16_t)kv.w;
        *(bf16x4*)(qb + o) = qo;
        *(bf16x4*)(kb + o) = ko;
        if (tid < (NE * NE / 4)) {
            float4 wv = *(const float4*)(w + tid * 4);
            bf16x4 wo;
            wo[0] = (bf16_t)wv.x; wo[1] = (bf16_t)wv.y; wo[2] = (bf16_t)wv.z; wo[3] = (bf16_t)wv.w;
            *(bf16x4*)(wb + tid * 4) = wo;
        }
    } else {
        const int vb = bid - 4096;
        const int h  = vb >> 6;
        const int t0 = (vb & 63) * 64;
        const int r  = threadIdx.x >> 6;   // 0..3
        const int cl = threadIdx.x & 63;
#pragma unroll
        for (int rep = 0; rep < 16; ++rep) {
            int i = rep * 4 + r;
            tile[cl][i] = (bf16_t)v[(t0 + i) * NE + h * DH + cl];
        }
        __syncthreads();
        const int r2  = threadIdx.x >> 5;        // 0..7
        const int cl2 = (threadIdx.x & 31) * 2;  // 0..62 even
        // inverse key permutation: old = n5*32 + n2*16 + n4*8 + n3*4 + n1n0
        const int ip = (cl2 & 32) + ((cl2 >> 2) & 1) * 16 + ((cl2 >> 4) & 1) * 8 +
                       ((cl2 >> 3) & 1) * 4 + (cl2 & 3);
#pragma unroll
        for (int rep = 0; rep < 8; ++rep) {
            int d = rep * 8 + r2;
            bf16x2 out;
            out[0] = tile[d][ip];
            out[1] = tile[d][ip + 1];
            *(bf16x2*)(vt + (h * DH + d) * S_LEN + t0 + cl2) = out;
        }
    }
}

// ---------------------------------------------------------------------------
// Flash attention v17 = v10 (round-3/5 verbatim, 79.7 us measured) + T5
// s_setprio(1) around the two MFMA clusters. The 2 co-resident blocks/CU
// are mutually independent; priority favors the block in its MFMA phase
// over the block issuing staging loads (m191: +4-7% attn precedent).
// z-split (r4/r9) and wave-geometry (r1/r7/r8) branches are closed:
// z-split reproducibly triples HBM WRITE (mechanism unmodelled), geometry
// changes lose more to occupancy/latency than they save in LDS traffic.
// ---------------------------------------------------------------------------
__global__ __launch_bounds__(512, 4) void attn(const bf16_t* __restrict__ qb,
                                               const bf16_t* __restrict__ kb,
                                               const bf16_t* __restrict__ vt,
                                               float* __restrict__ po,
                                               float* __restrict__ ls) {
    __shared__ __align__(16) bf16_t kbuf[2][64 * 72];
    __shared__ __align__(16) bf16_t vbuf[2][64 * 72];

    const int tid  = threadIdx.x;
    const int wave = tid >> 6;        // 0..7
    const int lane = tid & 63;
    const int l15  = lane & 15;
    const int quad = lane >> 4;
    const int h = blockIdx.x;
    const int x = blockIdx.y;

    const int sA = x;
    const int sB = 31 - x;
    const int n0 = x + 1;            // phase0 tile count
    const int b1 = sB + 1;           // phase1 first tile -> t0 base
    const int N  = 33;               // constant for all x

    const bf16_t* __restrict__ qh = qb + h * (S_LEN * DH);
    const bf16_t* __restrict__ kh = kb + h * (S_LEN * DH);
    const bf16_t* __restrict__ vh = vt + h * (DH * S_LEN);

    const int row0 = tid >> 3;        // 0..63
    const int tc8  = (tid & 7) * 8;   // 0..56
    const int stg  = row0 * 72 + tc8; // staging LDS offset (elements)
    const int frg  = l15 * 72 + quad * 8;  // fragment base offset (elements)

    f32x4 o_acc[4];
    f32x4 rs;                         // running row-sums via ones-MFMA
    bf16x8 qA[2];
    bf16x8 ones;
#pragma unroll
    for (int e = 0; e < 8; ++e) ones[e] = (bf16_t)1.0f;
    int s0 = sA * 128 + wave * 16;

    auto load_q = [&](int s0_) {
#pragma unroll
        for (int dc = 0; dc < 2; ++dc)
            qA[dc] = *(const bf16x8*)(qh + (s0_ + l15) * DH + dc * 32 + quad * 8);
    };
    auto reset_acc = [&]() {
#pragma unroll
        for (int db = 0; db < 4; ++db) o_acc[db] = (f32x4){0.f, 0.f, 0.f, 0.f};
        rs = (f32x4){0.f, 0.f, 0.f, 0.f};
    };
    auto epilogue = [&](int s0_, int slot) {
        float* poz = po + (size_t)(slot * NH + h) * S_LEN * DH;
#pragma unroll
        for (int r = 0; r < 4; ++r)
#pragma unroll
            for (int db = 0; db < 4; ++db)
                poz[(s0_ + quad * 4 + r) * DH + db * 16 + l15] = o_acc[db][r];
        if (l15 == 0) {
            float* lsz = ls + (size_t)(slot * NH + h) * S_LEN;
#pragma unroll
            for (int r = 0; r < 4; ++r) lsz[s0_ + quad * 4 + r] = rs[r];
        }
    };

    load_q(s0);
    reset_acc();

    {
        bf16x8 kr = *(const bf16x8*)(kh + row0 * DH + tc8);
        bf16x8 vr = *(const bf16x8*)(vh + row0 * S_LEN + tc8);
        *(bf16x8*)(kbuf[0] + stg) = kr;
        *(bf16x8*)(vbuf[0] + stg) = vr;
    }
    __syncthreads();

#pragma unroll 2
    for (int j = 0; j < N; ++j) {
        if (j == n0) {  // phase switch (block-uniform)
            epilogue(s0, 0);
            s0 = sB * 128 + wave * 16;
            load_q(s0);
            reset_acc();
        }
        const int t0 = (j < n0 ? j : b1 + (j - n0)) * 64;
        const bf16_t* kb_ = kbuf[j & 1];
        const bf16_t* vb_ = vbuf[j & 1];

        bf16x8 krn, vrn;
        const bool pf = (j + 1 < N);
        if (pf) {
            const int jn = j + 1;
            const int tn = (jn < n0 ? jn : b1 + (jn - n0)) * 64;
            krn = *(const bf16x8*)(kh + (tn + row0) * DH + tc8);
            vrn = *(const bf16x8*)(vh + row0 * S_LEN + tn + tc8);
        }

        // wave-uniform: this tile contributes only if some key <= some query
        if (t0 <= s0 + 15) {
            // ---- swapped QK^T: A = K fragments, B = Q (in registers)
            __builtin_amdgcn_s_setprio(1);
            f32x4 c_[4];
#pragma unroll
            for (int ch = 0; ch < 4; ++ch) {
                bf16x8 kB0 = *(const bf16x8*)(kb_ + frg + ch * (16 * 72));
                bf16x8 kB1 = *(const bf16x8*)(kb_ + frg + ch * (16 * 72) + 32);
                f32x4 zr = (f32x4){0.f, 0.f, 0.f, 0.f};
                zr = __builtin_amdgcn_mfma_f32_16x16x32_bf16(kB0, qA[0], zr, 0, 0, 0);
                zr = __builtin_amdgcn_mfma_f32_16x16x32_bf16(kB1, qA[1], zr, 0, 0, 0);
                c_[ch] = zr;
            }
            __builtin_amdgcn_s_setprio(0);

            // ---- mask + exp2 + lane-local pack into PV A-fragments
            // lane holds S^T[key=t0+16ch+4quad+r][query=s0+l15]
            const int query = s0 + l15;
            float p[4][4];
#pragma unroll
            for (int ch = 0; ch < 4; ++ch) {
                if (t0 + ch * 16 <= s0 + 15) {       // wave-uniform chunk-live
                    const bool edge = (t0 + ch * 16 + 15 > s0);
#pragma unroll
                    for (int r = 0; r < 4; ++r) {
                        float cc = c_[ch][r];
                        if (edge) {
                            int key = t0 + ch * 16 + quad * 4 + r;
                            if (key > query) cc = -INFINITY;
                        }
                        p[ch][r] = exp2f(cc);
                    }
                } else {
#pragma unroll
                    for (int r = 0; r < 4; ++r) p[ch][r] = 0.0f;
                }
            }

            bf16x8 pA[2];
#pragma unroll
            for (int kc = 0; kc < 2; ++kc) {
                bf16x8 t;
                t[0] = (bf16_t)p[2 * kc][0];     t[1] = (bf16_t)p[2 * kc][1];
                t[2] = (bf16_t)p[2 * kc][2];     t[3] = (bf16_t)p[2 * kc][3];
                t[4] = (bf16_t)p[2 * kc + 1][0]; t[5] = (bf16_t)p[2 * kc + 1][1];
                t[6] = (bf16_t)p[2 * kc + 1][2]; t[7] = (bf16_t)p[2 * kc + 1][3];
                pA[kc] = t;
            }

            // ---- row-sums + PV on the matrix pipe (T5 window)
            __builtin_amdgcn_s_setprio(1);
            rs = __builtin_amdgcn_mfma_f32_16x16x32_bf16(pA[0], ones, rs, 0, 0, 0);
            rs = __builtin_amdgcn_mfma_f32_16x16x32_bf16(pA[1], ones, rs, 0, 0, 0);

            // ---- PV: V pre-permuted -> single uniform b128 per fragment
#pragma unroll
            for (int db = 0; db < 4; ++db) {
#pragma unroll
                for (int kc = 0; kc < 2; ++kc) {
                    bf16x8 vB = *(const bf16x8*)(vb_ + frg + db * (16 * 72) + kc * 32);
                    o_acc[db] = __builtin_amdgcn_mfma_f32_16x16x32_bf16(pA[kc], vB, o_acc[db], 0, 0, 0);
                }
            }
            __builtin_amdgcn_s_setprio(0);
        }

        if (pf) {
            *(bf16x8*)(kbuf[(j + 1) & 1] + stg) = krn;
            *(bf16x8*)(vbuf[(j + 1) & 1] + stg) = vrn;
        }
        __syncthreads();
    }

    epilogue(s0, 1);
}

// ---------------------------------------------------------------------------
// Combine (unchanged): xb[row][h*64+d] = (o0 + o1) / (l0 + l1).
// ---------------------------------------------------------------------------
__global__ __launch_bounds__(256) void combine(const float* __restrict__ po,
                                               const float* __restrict__ ls,
                                               bf16_t* __restrict__ xb) {
    const int idx = blockIdx.x * 256 + threadIdx.x;
    const int row = idx >> 8;
    const int c   = (idx & 255) * 4;
    const int h   = c >> 6;
    const int d   = c & 63;
    const size_t base0 = (size_t)(h) * S_LEN * DH + row * DH + d;
    const size_t base1 = (size_t)(NH + h) * S_LEN * DH + row * DH + d;
    float4 o0 = *(const float4*)(po + base0);
    float4 o1 = *(const float4*)(po + base1);
    float l = ls[(size_t)h * S_LEN + row] + ls[(size_t)(NH + h) * S_LEN + row];
    float inv = 1.0f / l;
    bf16x4 out;
    out[0] = (bf16_t)((o0.x + o1.x) * inv);
    out[1] = (bf16_t)((o0.y + o1.y) * inv);
    out[2] = (bf16_t)((o0.z + o1.z) * inv);
    out[3] = (bf16_t)((o0.w + o1.w) * inv);
    *(bf16x4*)(xb + (size_t)row * NE + c) = out;
}

// ---------------------------------------------------------------------------
// Projection (round-5 m32 version, unchanged): Y = X(bf16) @ W^T(bf16).
// ---------------------------------------------------------------------------
__global__ __launch_bounds__(256, 4) void proj(const bf16_t* __restrict__ xb,
                                               const bf16_t* __restrict__ wb,
                                               float* __restrict__ y) {
    __shared__ __align__(16) bf16_t wbuf[2][64 * 72];
    const int tid  = threadIdx.x;
    const int wave = tid >> 6;
    const int lane = tid & 63;
    const int l15  = lane & 15;
    const int quad = lane >> 4;
    const int m0 = blockIdx.x * 128 + wave * 32;   // wave owns 32 rows
    const int n0 = blockIdx.y * 64;

    const int row0 = tid >> 3;        // 0..31 (second chunk adds 32)
    const int tc8  = (tid & 7) * 8;

    f32x4 acc[2][4];
#pragma unroll
    for (int g = 0; g < 2; ++g)
#pragma unroll
        for (int nb = 0; nb < 4; ++nb) acc[g][nb] = (f32x4){0.f, 0.f, 0.f, 0.f};

    {
        bf16x8 wr0 = *(const bf16x8*)(wb + (n0 + row0) * NE + tc8);
        bf16x8 wr1 = *(const bf16x8*)(wb + (n0 + row0 + 32) * NE + tc8);
        *(bf16x8*)(wbuf[0] + row0 * 72 + tc8) = wr0;
        *(bf16x8*)(wbuf[0] + (row0 + 32) * 72 + tc8) = wr1;
    }
    bf16x8 a[2][2];
#pragma unroll
    for (int g = 0; g < 2; ++g)
#pragma unroll
        for (int kc = 0; kc < 2; ++kc)
            a[g][kc] = *(const bf16x8*)(xb + (m0 + g * 16 + l15) * NE + kc * 32 + quad * 8);
    __syncthreads();

    for (int kt = 0; kt < 16; ++kt) {
        const bf16_t* wb_ = wbuf[kt & 1];
        const bool pf = (kt + 1 < 16);
        bf16x8 wr0, wr1, an[2][2];
        if (pf) {
            const int kn = (kt + 1) * 64;
            wr0 = *(const bf16x8*)(wb + (n0 + row0) * NE + kn + tc8);
            wr1 = *(const bf16x8*)(wb + (n0 + row0 + 32) * NE + kn + tc8);
#pragma unroll
            for (int g = 0; g < 2; ++g)
#pragma unroll
                for (int kc = 0; kc < 2; ++kc)
                    an[g][kc] = *(const bf16x8*)(xb + (m0 + g * 16 + l15) * NE + kn + kc * 32 + quad * 8);
        }

#pragma unroll
        for (int nb = 0; nb < 4; ++nb)
#pragma unroll
            for (int kc = 0; kc < 2; ++kc) {
                bf16x8 b = *(const bf16x8*)(wb_ + (nb * 16 + l15) * 72 + kc * 32 + quad * 8);
#pragma unroll
                for (int g = 0; g < 2; ++g)
                    acc[g][nb] = __builtin_amdgcn_mfma_f32_16x16x32_bf16(a[g][kc], b, acc[g][nb], 0, 0, 0);
            }

        if (pf) {
            *(bf16x8*)(wbuf[(kt + 1) & 1] + row0 * 72 + tc8) = wr0;
            *(bf16x8*)(wbuf[(kt + 1) & 1] + (row0 + 32) * 72 + tc8) = wr1;
#pragma unroll
            for (int g = 0; g < 2; ++g)
#pragma unroll
                for (int kc = 0; kc < 2; ++kc) a[g][kc] = an[g][kc];
        }
        __syncthreads();
    }

#pragma unroll
    for (int g = 0; g < 2; ++g)
#pragma unroll
        for (int nb = 0; nb < 4; ++nb)
#pragma unroll
            for (int r = 0; r < 4; ++r)
                y[(m0 + g * 16 + quad * 4 + r) * NE + n0 + nb * 16 + l15] = acc[g][nb][r];
}

extern "C" void kernel_launch(void* const* d_in, const int* in_sizes, int n_in,
                              void* d_out, int out_size, void* d_ws, size_t ws_size,
                              hipStream_t stream) {
    const float* q = (const float*)d_in[0];
    const float* k = (const float*)d_in[1];
    const float* v = (const float*)d_in[2];
    const float* w = (const float*)d_in[3];
    float* y = (float*)d_out;

    // ws: bf16 {qb 4M | kb 4M | vt 4M | wb 1M | xb 4M} then fp32 {po 8M | ls 128K}
    bf16_t* ws = (bf16_t*)d_ws;
    bf16_t* qb = ws;
    bf16_t* kb = qb + 4 * 1024 * 1024;
    bf16_t* vt = kb + 4 * 1024 * 1024;
    bf16_t* wb = vt + 4 * 1024 * 1024;
    bf16_t* xb = wb + 1024 * 1024;
    float*  po = (float*)(xb + 4 * 1024 * 1024);
    float*  ls = po + (size_t)2 * NH * S_LEN * DH;

    pack_all<<<dim3(4096 + 1024), dim3(256), 0, stream>>>(q, k, w, v, qb, kb, wb, vt);
    attn<<<dim3(NH, 32), dim3(512), 0, stream>>>(qb, kb, vt, po, ls);
    combine<<<dim3(4096), dim3(256), 0, stream>>>(po, ls, xb);
    proj<<<dim3(S_LEN / 128, NE / 64), dim3(256), 0, stream>>>(xb, wb, y);
}

// Round 11
// 192.409 us; speedup vs baseline: 1.1934x; 1.0151x over previous
//
#include <hip/hip_runtime.h>

#define S_LEN 4096
#define NH 16
#define DH 64
#define NE 1024

typedef __bf16 bf16_t;
typedef __bf16 bf16x8 __attribute__((ext_vector_type(8)));
typedef __bf16 bf16x4 __attribute__((ext_vector_type(4)));
typedef __bf16 bf16x2 __attribute__((ext_vector_type(2)));
typedef float  f32x4  __attribute__((ext_vector_type(4)));

#define QSCALE 0.180336879f  // 0.125 * log2(e): softmax in exp2 domain

// ---------------------------------------------------------------------------
// Fused pack kernel (round-5 version, unchanged). Blocks [0,4096): q,k ->
// head-major bf16 (q pre-scaled QSCALE) + W -> bf16. Blocks [4096,5120):
// V -> vt[h][d][t'] transpose with the within-64 key permutation
// (vt[pos] = V[ip(pos)]) so attn's PV B-fragment is one contiguous b128.
// Lanes write CONTIGUOUS vt addresses, read inverse-permuted LDS entries.
// ---------------------------------------------------------------------------
__global__ __launch_bounds__(256) void pack_all(const float* __restrict__ q,
                                                const float* __restrict__ k,
                                                const float* __restrict__ w,
                                                const float* __restrict__ v,
                                                bf16_t* __restrict__ qb,
                                                bf16_t* __restrict__ kb,
                                                bf16_t* __restrict__ wb,
                                                bf16_t* __restrict__ vt) {
    __shared__ bf16_t tile[64][65];
    const int bid = blockIdx.x;
    if (bid < 4096) {
        const int tid = bid * 256 + threadIdx.x;
        const int e = tid * 4;
        const int s = e >> 10;
        const int c = e & (NE - 1);
        const int h = c >> 6;
        const int d = c & (DH - 1);
        const int o = (h * S_LEN + s) * DH + d;
        float4 qv = *(const float4*)(q + e);
        float4 kv = *(const float4*)(k + e);
        bf16x4 qo, ko;
        qo[0] = (bf16_t)(qv.x * QSCALE); qo[1] = (bf16_t)(qv.y * QSCALE);
        qo[2] = (bf16_t)(qv.z * QSCALE); qo[3] = (bf16_t)(qv.w * QSCALE);
        ko[0] = (bf16_t)kv.x; ko[1] = (bf16_t)kv.y; ko[2] = (bf16_t)kv.z; ko[3] = (bf16_t)kv.w;
        *(bf16x4*)(qb + o) = qo;
        *(bf16x4*)(kb + o) = ko;
        if (tid < (NE * NE / 4)) {
            float4 wv = *(const float4*)(w + tid * 4);
            bf16x4 wo;
            wo[0] = (bf16_t)wv.x; wo[1] = (bf16_t)wv.y; wo[2] = (bf16_t)wv.z; wo[3] = (bf16_t)wv.w;
            *(bf16x4*)(wb + tid * 4) = wo;
        }
    } else {
        const int vb = bid - 4096;
        const int h  = vb >> 6;
        const int t0 = (vb & 63) * 64;
        const int r  = threadIdx.x >> 6;   // 0..3
        const int cl = threadIdx.x & 63;
#pragma unroll
        for (int rep = 0; rep < 16; ++rep) {
            int i = rep * 4 + r;
            tile[cl][i] = (bf16_t)v[(t0 + i) * NE + h * DH + cl];
        }
        __syncthreads();
        const int r2  = threadIdx.x >> 5;        // 0..7
        const int cl2 = (threadIdx.x & 31) * 2;  // 0..62 even
        // inverse key permutation: old = n5*32 + n2*16 + n4*8 + n3*4 + n1n0
        const int ip = (cl2 & 32) + ((cl2 >> 2) & 1) * 16 + ((cl2 >> 4) & 1) * 8 +
                       ((cl2 >> 3) & 1) * 4 + (cl2 & 3);
#pragma unroll
        for (int rep = 0; rep < 8; ++rep) {
            int d = rep * 8 + r2;
            bf16x2 out;
            out[0] = tile[d][ip];
            out[1] = tile[d][ip + 1];
            *(bf16x2*)(vt + (h * DH + d) * S_LEN + t0 + cl2) = out;
        }
    }
}

// ---------------------------------------------------------------------------
// Flash attention v18 = v10 body (79.7 us, best measured) with the 2-slot
// double-buffer replaced by a 4-SLOT LDS RING: pair (j, j+1) reads slots
// j&3/(j+1)&3 while tiles j+2/j+3 are global-prefetched (issue at pair
// start) and committed to the two disjoint slots at pair end -> ONE
// __syncthreads per 2 tiles (17 barriers vs 33). Slot safety: slot (j+2)&3
// was last read at pair j-2 (>=1 barrier ago); pair-p writes vs pair-(p+2)
// reads are separated by the pair-p barrier. Residency is grid-limited at
// 2 blocks/CU, so the 73728B ring costs nothing. Targets the ~2.4K cy/
// tile-round barrier-drain + wave-skew residue (the only unaddressed term
// in the per-CU cycle model). setprio removed (r10: exactly neutral).
// ---------------------------------------------------------------------------
__global__ __launch_bounds__(512, 4) void attn(const bf16_t* __restrict__ qb,
                                               const bf16_t* __restrict__ kb,
                                               const bf16_t* __restrict__ vt,
                                               float* __restrict__ po,
                                               float* __restrict__ ls) {
    __shared__ __align__(16) bf16_t kbuf[4][64 * 72];
    __shared__ __align__(16) bf16_t vbuf[4][64 * 72];

    const int tid  = threadIdx.x;
    const int wave = tid >> 6;        // 0..7
    const int lane = tid & 63;
    const int l15  = lane & 15;
    const int quad = lane >> 4;
    const int h = blockIdx.x;
    const int x = blockIdx.y;

    const int sA = x;
    const int sB = 31 - x;
    const int n0 = x + 1;            // phase0 tile count
    const int b1 = sB + 1;           // phase1 first tile -> t0 base
    const int N  = 33;               // constant for all x

    const bf16_t* __restrict__ qh = qb + h * (S_LEN * DH);
    const bf16_t* __restrict__ kh = kb + h * (S_LEN * DH);
    const bf16_t* __restrict__ vh = vt + h * (DH * S_LEN);

    const int row0 = tid >> 3;        // 0..63
    const int tc8  = (tid & 7) * 8;   // 0..56
    const int stg  = row0 * 72 + tc8; // staging LDS offset (elements)
    const int frg  = l15 * 72 + quad * 8;  // fragment base offset (elements)

    f32x4 o_acc[4];
    f32x4 rs;                         // running row-sums via ones-MFMA
    bf16x8 qA[2];
    bf16x8 ones;
#pragma unroll
    for (int e = 0; e < 8; ++e) ones[e] = (bf16_t)1.0f;
    int s0 = sA * 128 + wave * 16;

    auto t0_of = [&](int j) { return (j < n0 ? j : b1 + (j - n0)) * 64; };

    auto load_q = [&](int s0_) {
#pragma unroll
        for (int dc = 0; dc < 2; ++dc)
            qA[dc] = *(const bf16x8*)(qh + (s0_ + l15) * DH + dc * 32 + quad * 8);
    };
    auto reset_acc = [&]() {
#pragma unroll
        for (int db = 0; db < 4; ++db) o_acc[db] = (f32x4){0.f, 0.f, 0.f, 0.f};
        rs = (f32x4){0.f, 0.f, 0.f, 0.f};
    };
    auto epilogue = [&](int s0_, int slot) {
        float* poz = po + (size_t)(slot * NH + h) * S_LEN * DH;
#pragma unroll
        for (int r = 0; r < 4; ++r)
#pragma unroll
            for (int db = 0; db < 4; ++db)
                poz[(s0_ + quad * 4 + r) * DH + db * 16 + l15] = o_acc[db][r];
        if (l15 == 0) {
            float* lsz = ls + (size_t)(slot * NH + h) * S_LEN;
#pragma unroll
            for (int r = 0; r < 4; ++r) lsz[s0_ + quad * 4 + r] = rs[r];
        }
    };

    load_q(s0);
    reset_acc();

    // prologue: stage tiles 0 and 1 into ring slots 0, 1
#pragma unroll
    for (int jj = 0; jj < 2; ++jj) {
        const int t0p = t0_of(jj);
        bf16x8 kr = *(const bf16x8*)(kh + (t0p + row0) * DH + tc8);
        bf16x8 vr = *(const bf16x8*)(vh + row0 * S_LEN + t0p + tc8);
        *(bf16x8*)(kbuf[jj] + stg) = kr;
        *(bf16x8*)(vbuf[jj] + stg) = vr;
    }
    __syncthreads();

    bf16x8 krn[2], vrn[2];            // prefetch regs for the next pair

#pragma unroll 2
    for (int j = 0; j < N; ++j) {
        if (j == n0) {  // phase switch (block-uniform)
            epilogue(s0, 0);
            s0 = sB * 128 + wave * 16;
            load_q(s0);
            reset_acc();
        }
        const int t0 = t0_of(j);
        const bf16_t* kb_ = kbuf[j & 3];
        const bf16_t* vb_ = vbuf[j & 3];

        if ((j & 1) == 0) {
            // pair start: issue global loads for tiles j+2, j+3 (uniform guards)
#pragma unroll
            for (int u = 0; u < 2; ++u) {
                const int jn = j + 2 + u;
                if (jn < N) {
                    const int tn = t0_of(jn);
                    krn[u] = *(const bf16x8*)(kh + (tn + row0) * DH + tc8);
                    vrn[u] = *(const bf16x8*)(vh + row0 * S_LEN + tn + tc8);
                }
            }
        }

        // wave-uniform: this tile contributes only if some key <= some query
        if (t0 <= s0 + 15) {
            // ---- swapped QK^T: A = K fragments, B = Q (in registers)
            f32x4 c_[4];
#pragma unroll
            for (int ch = 0; ch < 4; ++ch) {
                bf16x8 kB0 = *(const bf16x8*)(kb_ + frg + ch * (16 * 72));
                bf16x8 kB1 = *(const bf16x8*)(kb_ + frg + ch * (16 * 72) + 32);
                f32x4 zr = (f32x4){0.f, 0.f, 0.f, 0.f};
                zr = __builtin_amdgcn_mfma_f32_16x16x32_bf16(kB0, qA[0], zr, 0, 0, 0);
                zr = __builtin_amdgcn_mfma_f32_16x16x32_bf16(kB1, qA[1], zr, 0, 0, 0);
                c_[ch] = zr;
            }

            // ---- mask + exp2 + lane-local pack into PV A-fragments
            // lane holds S^T[key=t0+16ch+4quad+r][query=s0+l15]
            const int query = s0 + l15;
            float p[4][4];
#pragma unroll
            for (int ch = 0; ch < 4; ++ch) {
                if (t0 + ch * 16 <= s0 + 15) {       // wave-uniform chunk-live
                    const bool edge = (t0 + ch * 16 + 15 > s0);
#pragma unroll
                    for (int r = 0; r < 4; ++r) {
                        float cc = c_[ch][r];
                        if (edge) {
                            int key = t0 + ch * 16 + quad * 4 + r;
                            if (key > query) cc = -INFINITY;
                        }
                        p[ch][r] = exp2f(cc);
                    }
                } else {
#pragma unroll
                    for (int r = 0; r < 4; ++r) p[ch][r] = 0.0f;
                }
            }

            bf16x8 pA[2];
#pragma unroll
            for (int kc = 0; kc < 2; ++kc) {
                bf16x8 t;
                t[0] = (bf16_t)p[2 * kc][0];     t[1] = (bf16_t)p[2 * kc][1];
                t[2] = (bf16_t)p[2 * kc][2];     t[3] = (bf16_t)p[2 * kc][3];
                t[4] = (bf16_t)p[2 * kc + 1][0]; t[5] = (bf16_t)p[2 * kc + 1][1];
                t[6] = (bf16_t)p[2 * kc + 1][2]; t[7] = (bf16_t)p[2 * kc + 1][3];
                pA[kc] = t;
            }

            // ---- row-sums on the matrix pipe (replaces 16 VALU adds)
            rs = __builtin_amdgcn_mfma_f32_16x16x32_bf16(pA[0], ones, rs, 0, 0, 0);
            rs = __builtin_amdgcn_mfma_f32_16x16x32_bf16(pA[1], ones, rs, 0, 0, 0);

            // ---- PV: V pre-permuted -> single uniform b128 per fragment
#pragma unroll
            for (int db = 0; db < 4; ++db) {
#pragma unroll
                for (int kc = 0; kc < 2; ++kc) {
                    bf16x8 vB = *(const bf16x8*)(vb_ + frg + db * (16 * 72) + kc * 32);
                    o_acc[db] = __builtin_amdgcn_mfma_f32_16x16x32_bf16(pA[kc], vB, o_acc[db], 0, 0, 0);
                }
            }
        }

        if (j & 1) {
            // pair end: commit staged tiles j+1, j+2 to their ring slots,
            // then ONE barrier for the pair.
#pragma unroll
            for (int u = 0; u < 2; ++u) {
                const int jn = j + 1 + u;
                if (jn < N) {
                    *(bf16x8*)(kbuf[jn & 3] + stg) = krn[u];
                    *(bf16x8*)(vbuf[jn & 3] + stg) = vrn[u];
                }
            }
            __syncthreads();
        }
    }

    epilogue(s0, 1);
}

// ---------------------------------------------------------------------------
// Combine (unchanged): xb[row][h*64+d] = (o0 + o1) / (l0 + l1).
// ---------------------------------------------------------------------------
__global__ __launch_bounds__(256) void combine(const float* __restrict__ po,
                                               const float* __restrict__ ls,
                                               bf16_t* __restrict__ xb) {
    const int idx = blockIdx.x * 256 + threadIdx.x;
    const int row = idx >> 8;
    const int c   = (idx & 255) * 4;
    const int h   = c >> 6;
    const int d   = c & 63;
    const size_t base0 = (size_t)(h) * S_LEN * DH + row * DH + d;
    const size_t base1 = (size_t)(NH + h) * S_LEN * DH + row * DH + d;
    float4 o0 = *(const float4*)(po + base0);
    float4 o1 = *(const float4*)(po + base1);
    float l = ls[(size_t)h * S_LEN + row] + ls[(size_t)(NH + h) * S_LEN + row];
    float inv = 1.0f / l;
    bf16x4 out;
    out[0] = (bf16_t)((o0.x + o1.x) * inv);
    out[1] = (bf16_t)((o0.y + o1.y) * inv);
    out[2] = (bf16_t)((o0.z + o1.z) * inv);
    out[3] = (bf16_t)((o0.w + o1.w) * inv);
    *(bf16x4*)(xb + (size_t)row * NE + c) = out;
}

// ---------------------------------------------------------------------------
// Projection (round-5 m32 version, unchanged): Y = X(bf16) @ W^T(bf16).
// ---------------------------------------------------------------------------
__global__ __launch_bounds__(256, 4) void proj(const bf16_t* __restrict__ xb,
                                               const bf16_t* __restrict__ wb,
                                               float* __restrict__ y) {
    __shared__ __align__(16) bf16_t wbuf[2][64 * 72];
    const int tid  = threadIdx.x;
    const int wave = tid >> 6;
    const int lane = tid & 63;
    const int l15  = lane & 15;
    const int quad = lane >> 4;
    const int m0 = blockIdx.x * 128 + wave * 32;   // wave owns 32 rows
    const int n0 = blockIdx.y * 64;

    const int row0 = tid >> 3;        // 0..31 (second chunk adds 32)
    const int tc8  = (tid & 7) * 8;

    f32x4 acc[2][4];
#pragma unroll
    for (int g = 0; g < 2; ++g)
#pragma unroll
        for (int nb = 0; nb < 4; ++nb) acc[g][nb] = (f32x4){0.f, 0.f, 0.f, 0.f};

    {
        bf16x8 wr0 = *(const bf16x8*)(wb + (n0 + row0) * NE + tc8);
        bf16x8 wr1 = *(const bf16x8*)(wb + (n0 + row0 + 32) * NE + tc8);
        *(bf16x8*)(wbuf[0] + row0 * 72 + tc8) = wr0;
        *(bf16x8*)(wbuf[0] + (row0 + 32) * 72 + tc8) = wr1;
    }
    bf16x8 a[2][2];
#pragma unroll
    for (int g = 0; g < 2; ++g)
#pragma unroll
        for (int kc = 0; kc < 2; ++kc)
            a[g][kc] = *(const bf16x8*)(xb + (m0 + g * 16 + l15) * NE + kc * 32 + quad * 8);
    __syncthreads();

    for (int kt = 0; kt < 16; ++kt) {
        const bf16_t* wb_ = wbuf[kt & 1];
        const bool pf = (kt + 1 < 16);
        bf16x8 wr0, wr1, an[2][2];
        if (pf) {
            const int kn = (kt + 1) * 64;
            wr0 = *(const bf16x8*)(wb + (n0 + row0) * NE + kn + tc8);
            wr1 = *(const bf16x8*)(wb + (n0 + row0 + 32) * NE + kn + tc8);
#pragma unroll
            for (int g = 0; g < 2; ++g)
#pragma unroll
                for (int kc = 0; kc < 2; ++kc)
                    an[g][kc] = *(const bf16x8*)(xb + (m0 + g * 16 + l15) * NE + kn + kc * 32 + quad * 8);
        }

#pragma unroll
        for (int nb = 0; nb < 4; ++nb)
#pragma unroll
            for (int kc = 0; kc < 2; ++kc) {
                bf16x8 b = *(const bf16x8*)(wb_ + (nb * 16 + l15) * 72 + kc * 32 + quad * 8);
#pragma unroll
                for (int g = 0; g < 2; ++g)
                    acc[g][nb] = __builtin_amdgcn_mfma_f32_16x16x32_bf16(a[g][kc], b, acc[g][nb], 0, 0, 0);
            }

        if (pf) {
            *(bf16x8*)(wbuf[(kt + 1) & 1] + row0 * 72 + tc8) = wr0;
            *(bf16x8*)(wbuf[(kt + 1) & 1] + (row0 + 32) * 72 + tc8) = wr1;
#pragma unroll
            for (int g = 0; g < 2; ++g)
#pragma unroll
                for (int kc = 0; kc < 2; ++kc) a[g][kc] = an[g][kc];
        }
        __syncthreads();
    }

#pragma unroll
    for (int g = 0; g < 2; ++g)
#pragma unroll
        for (int nb = 0; nb < 4; ++nb)
#pragma unroll
            for (int r = 0; r < 4; ++r)
                y[(m0 + g * 16 + quad * 4 + r) * NE + n0 + nb * 16 + l15] = acc[g][nb][r];
}

extern "C" void kernel_launch(void* const* d_in, const int* in_sizes, int n_in,
                              void* d_out, int out_size, void* d_ws, size_t ws_size,
                              hipStream_t stream) {
    const float* q = (const float*)d_in[0];
    const float* k = (const float*)d_in[1];
    const float* v = (const float*)d_in[2];
    const float* w = (const float*)d_in[3];
    float* y = (float*)d_out;

    // ws: bf16 {qb 4M | kb 4M | vt 4M | wb 1M | xb 4M} then fp32 {po 8M | ls 128K}
    bf16_t* ws = (bf16_t*)d_ws;
    bf16_t* qb = ws;
    bf16_t* kb = qb + 4 * 1024 * 1024;
    bf16_t* vt = kb + 4 * 1024 * 1024;
    bf16_t* wb = vt + 4 * 1024 * 1024;
    bf16_t* xb = wb + 1024 * 1024;
    float*  po = (float*)(xb + 4 * 1024 * 1024);
    float*  ls = po + (size_t)2 * NH * S_LEN * DH;

    pack_all<<<dim3(4096 + 1024), dim3(256), 0, stream>>>(q, k, w, v, qb, kb, wb, vt);
    attn<<<dim3(NH, 32), dim3(512), 0, stream>>>(qb, kb, vt, po, ls);
    combine<<<dim3(4096), dim3(256), 0, stream>>>(po, ls, xb);
    proj<<<dim3(S_LEN / 128, NE / 64), dim3(256), 0, stream>>>(xb, wb, y);
}

// Round 12
// 179.850 us; speedup vs baseline: 1.2768x; 1.0698x over previous
//
#include <hip/hip_runtime.h>

#define S_LEN 4096
#define NH 16
#define DH 64
#define NE 1024

typedef __bf16 bf16_t;
typedef __bf16 bf16x8 __attribute__((ext_vector_type(8)));
typedef __bf16 bf16x4 __attribute__((ext_vector_type(4)));
typedef __bf16 bf16x2 __attribute__((ext_vector_type(2)));
typedef float  f32x4  __attribute__((ext_vector_type(4)));

#define QSCALE 0.180336879f  // 0.125 * log2(e): softmax in exp2 domain

// ---------------------------------------------------------------------------
// Fused pack kernel (round-5 version, unchanged). Blocks [0,4096): q,k ->
// head-major bf16 (q pre-scaled QSCALE) + W -> bf16. Blocks [4096,5120):
// V -> vt[h][d][t'] transpose with the within-64 key permutation
// (vt[pos] = V[ip(pos)]) so attn's PV B-fragment is one contiguous b128.
// Lanes write CONTIGUOUS vt addresses, read inverse-permuted LDS entries.
// ---------------------------------------------------------------------------
__global__ __launch_bounds__(256) void pack_all(const float* __restrict__ q,
                                                const float* __restrict__ k,
                                                const float* __restrict__ w,
                                                const float* __restrict__ v,
                                                bf16_t* __restrict__ qb,
                                                bf16_t* __restrict__ kb,
                                                bf16_t* __restrict__ wb,
                                                bf16_t* __restrict__ vt) {
    __shared__ bf16_t tile[64][65];
    const int bid = blockIdx.x;
    if (bid < 4096) {
        const int tid = bid * 256 + threadIdx.x;
        const int e = tid * 4;
        const int s = e >> 10;
        const int c = e & (NE - 1);
        const int h = c >> 6;
        const int d = c & (DH - 1);
        const int o = (h * S_LEN + s) * DH + d;
        float4 qv = *(const float4*)(q + e);
        float4 kv = *(const float4*)(k + e);
        bf16x4 qo, ko;
        qo[0] = (bf16_t)(qv.x * QSCALE); qo[1] = (bf16_t)(qv.y * QSCALE);
        qo[2] = (bf16_t)(qv.z * QSCALE); qo[3] = (bf16_t)(qv.w * QSCALE);
        ko[0] = (bf16_t)kv.x; ko[1] = (bf16_t)kv.y; ko[2] = (bf16_t)kv.z; ko[3] = (bf16_t)kv.w;
        *(bf16x4*)(qb + o) = qo;
        *(bf16x4*)(kb + o) = ko;
        if (tid < (NE * NE / 4)) {
            float4 wv = *(const float4*)(w + tid * 4);
            bf16x4 wo;
            wo[0] = (bf16_t)wv.x; wo[1] = (bf16_t)wv.y; wo[2] = (bf16_t)wv.z; wo[3] = (bf16_t)wv.w;
            *(bf16x4*)(wb + tid * 4) = wo;
        }
    } else {
        const int vb = bid - 4096;
        const int h  = vb >> 6;
        const int t0 = (vb & 63) * 64;
        const int r  = threadIdx.x >> 6;   // 0..3
        const int cl = threadIdx.x & 63;
#pragma unroll
        for (int rep = 0; rep < 16; ++rep) {
            int i = rep * 4 + r;
            tile[cl][i] = (bf16_t)v[(t0 + i) * NE + h * DH + cl];
        }
        __syncthreads();
        const int r2  = threadIdx.x >> 5;        // 0..7
        const int cl2 = (threadIdx.x & 31) * 2;  // 0..62 even
        // inverse key permutation: old = n5*32 + n2*16 + n4*8 + n3*4 + n1n0
        const int ip = (cl2 & 32) + ((cl2 >> 2) & 1) * 16 + ((cl2 >> 4) & 1) * 8 +
                       ((cl2 >> 3) & 1) * 4 + (cl2 & 3);
#pragma unroll
        for (int rep = 0; rep < 8; ++rep) {
            int d = rep * 8 + r2;
            bf16x2 out;
            out[0] = tile[d][ip];
            out[1] = tile[d][ip + 1];
            *(bf16x2*)(vt + (h * DH + d) * S_LEN + t0 + cl2) = out;
        }
    }
}

// ---------------------------------------------------------------------------
// Flash attention v19 = v18 (4-slot ring, 80.0 us) with the softmax VALU
// stream shrunk. Diagnosis (r11): VALUBusy 57% over 132 wave-tiles/SIMD
// = ~430 VALU instr/wave-tile -- dominated by libm exp2f expansion
// (~6-10 instr each without fast-math) and per-element key reconstruction
// in the causal mask. Fixes: (1) __builtin_amdgcn_exp2f -> single
// v_exp_f32 (exact semantics: exp2 domain, exp(-inf)=0, |S|<~40 so no
// range handling needed, bias-free scheme cancels in combine);
// (2) mask limit hoisted per chunk: lim = query - (t0+ch*16+quad*4),
// element test is literal-vs-reg (r > lim). Structure unchanged.
// ---------------------------------------------------------------------------
__global__ __launch_bounds__(512, 4) void attn(const bf16_t* __restrict__ qb,
                                               const bf16_t* __restrict__ kb,
                                               const bf16_t* __restrict__ vt,
                                               float* __restrict__ po,
                                               float* __restrict__ ls) {
    __shared__ __align__(16) bf16_t kbuf[4][64 * 72];
    __shared__ __align__(16) bf16_t vbuf[4][64 * 72];

    const int tid  = threadIdx.x;
    const int wave = tid >> 6;        // 0..7
    const int lane = tid & 63;
    const int l15  = lane & 15;
    const int quad = lane >> 4;
    const int h = blockIdx.x;
    const int x = blockIdx.y;

    const int sA = x;
    const int sB = 31 - x;
    const int n0 = x + 1;            // phase0 tile count
    const int b1 = sB + 1;           // phase1 first tile -> t0 base
    const int N  = 33;               // constant for all x

    const bf16_t* __restrict__ qh = qb + h * (S_LEN * DH);
    const bf16_t* __restrict__ kh = kb + h * (S_LEN * DH);
    const bf16_t* __restrict__ vh = vt + h * (DH * S_LEN);

    const int row0 = tid >> 3;        // 0..63
    const int tc8  = (tid & 7) * 8;   // 0..56
    const int stg  = row0 * 72 + tc8; // staging LDS offset (elements)
    const int frg  = l15 * 72 + quad * 8;  // fragment base offset (elements)

    f32x4 o_acc[4];
    f32x4 rs;                         // running row-sums via ones-MFMA
    bf16x8 qA[2];
    bf16x8 ones;
#pragma unroll
    for (int e = 0; e < 8; ++e) ones[e] = (bf16_t)1.0f;
    int s0 = sA * 128 + wave * 16;

    auto t0_of = [&](int j) { return (j < n0 ? j : b1 + (j - n0)) * 64; };

    auto load_q = [&](int s0_) {
#pragma unroll
        for (int dc = 0; dc < 2; ++dc)
            qA[dc] = *(const bf16x8*)(qh + (s0_ + l15) * DH + dc * 32 + quad * 8);
    };
    auto reset_acc = [&]() {
#pragma unroll
        for (int db = 0; db < 4; ++db) o_acc[db] = (f32x4){0.f, 0.f, 0.f, 0.f};
        rs = (f32x4){0.f, 0.f, 0.f, 0.f};
    };
    auto epilogue = [&](int s0_, int slot) {
        float* poz = po + (size_t)(slot * NH + h) * S_LEN * DH;
#pragma unroll
        for (int r = 0; r < 4; ++r)
#pragma unroll
            for (int db = 0; db < 4; ++db)
                poz[(s0_ + quad * 4 + r) * DH + db * 16 + l15] = o_acc[db][r];
        if (l15 == 0) {
            float* lsz = ls + (size_t)(slot * NH + h) * S_LEN;
#pragma unroll
            for (int r = 0; r < 4; ++r) lsz[s0_ + quad * 4 + r] = rs[r];
        }
    };

    load_q(s0);
    reset_acc();

    // prologue: stage tiles 0 and 1 into ring slots 0, 1
#pragma unroll
    for (int jj = 0; jj < 2; ++jj) {
        const int t0p = t0_of(jj);
        bf16x8 kr = *(const bf16x8*)(kh + (t0p + row0) * DH + tc8);
        bf16x8 vr = *(const bf16x8*)(vh + row0 * S_LEN + t0p + tc8);
        *(bf16x8*)(kbuf[jj] + stg) = kr;
        *(bf16x8*)(vbuf[jj] + stg) = vr;
    }
    __syncthreads();

    bf16x8 krn[2], vrn[2];            // prefetch regs for the next pair

#pragma unroll 2
    for (int j = 0; j < N; ++j) {
        if (j == n0) {  // phase switch (block-uniform)
            epilogue(s0, 0);
            s0 = sB * 128 + wave * 16;
            load_q(s0);
            reset_acc();
        }
        const int t0 = t0_of(j);
        const bf16_t* kb_ = kbuf[j & 3];
        const bf16_t* vb_ = vbuf[j & 3];

        if ((j & 1) == 0) {
            // pair start: issue global loads for tiles j+2, j+3 (uniform guards)
#pragma unroll
            for (int u = 0; u < 2; ++u) {
                const int jn = j + 2 + u;
                if (jn < N) {
                    const int tn = t0_of(jn);
                    krn[u] = *(const bf16x8*)(kh + (tn + row0) * DH + tc8);
                    vrn[u] = *(const bf16x8*)(vh + row0 * S_LEN + tn + tc8);
                }
            }
        }

        // wave-uniform: this tile contributes only if some key <= some query
        if (t0 <= s0 + 15) {
            // ---- swapped QK^T: A = K fragments, B = Q (in registers)
            f32x4 c_[4];
#pragma unroll
            for (int ch = 0; ch < 4; ++ch) {
                bf16x8 kB0 = *(const bf16x8*)(kb_ + frg + ch * (16 * 72));
                bf16x8 kB1 = *(const bf16x8*)(kb_ + frg + ch * (16 * 72) + 32);
                f32x4 zr = (f32x4){0.f, 0.f, 0.f, 0.f};
                zr = __builtin_amdgcn_mfma_f32_16x16x32_bf16(kB0, qA[0], zr, 0, 0, 0);
                zr = __builtin_amdgcn_mfma_f32_16x16x32_bf16(kB1, qA[1], zr, 0, 0, 0);
                c_[ch] = zr;
            }

            // ---- mask + exp2 + lane-local pack into PV A-fragments
            // lane holds S^T[key=t0+16ch+4quad+r][query=s0+l15].
            // Mask limit hoisted: element (ch,r) masked iff r > lim(ch).
            const int query = s0 + l15;
            float p[4][4];
#pragma unroll
            for (int ch = 0; ch < 4; ++ch) {
                if (t0 + ch * 16 <= s0 + 15) {       // wave-uniform chunk-live
                    const bool edge = (t0 + ch * 16 + 15 > s0);
                    const int lim = query - (t0 + ch * 16 + quad * 4);
#pragma unroll
                    for (int r = 0; r < 4; ++r) {
                        float cc = c_[ch][r];
                        if (edge && r > lim) cc = -INFINITY;
                        p[ch][r] = __builtin_amdgcn_exp2f(cc);
                    }
                } else {
#pragma unroll
                    for (int r = 0; r < 4; ++r) p[ch][r] = 0.0f;
                }
            }

            bf16x8 pA[2];
#pragma unroll
            for (int kc = 0; kc < 2; ++kc) {
                bf16x8 t;
                t[0] = (bf16_t)p[2 * kc][0];     t[1] = (bf16_t)p[2 * kc][1];
                t[2] = (bf16_t)p[2 * kc][2];     t[3] = (bf16_t)p[2 * kc][3];
                t[4] = (bf16_t)p[2 * kc + 1][0]; t[5] = (bf16_t)p[2 * kc + 1][1];
                t[6] = (bf16_t)p[2 * kc + 1][2]; t[7] = (bf16_t)p[2 * kc + 1][3];
                pA[kc] = t;
            }

            // ---- row-sums on the matrix pipe (replaces 16 VALU adds)
            rs = __builtin_amdgcn_mfma_f32_16x16x32_bf16(pA[0], ones, rs, 0, 0, 0);
            rs = __builtin_amdgcn_mfma_f32_16x16x32_bf16(pA[1], ones, rs, 0, 0, 0);

            // ---- PV: V pre-permuted -> single uniform b128 per fragment
#pragma unroll
            for (int db = 0; db < 4; ++db) {
#pragma unroll
                for (int kc = 0; kc < 2; ++kc) {
                    bf16x8 vB = *(const bf16x8*)(vb_ + frg + db * (16 * 72) + kc * 32);
                    o_acc[db] = __builtin_amdgcn_mfma_f32_16x16x32_bf16(pA[kc], vB, o_acc[db], 0, 0, 0);
                }
            }
        }

        if (j & 1) {
            // pair end: commit staged tiles j+1, j+2 to their ring slots,
            // then ONE barrier for the pair.
#pragma unroll
            for (int u = 0; u < 2; ++u) {
                const int jn = j + 1 + u;
                if (jn < N) {
                    *(bf16x8*)(kbuf[jn & 3] + stg) = krn[u];
                    *(bf16x8*)(vbuf[jn & 3] + stg) = vrn[u];
                }
            }
            __syncthreads();
        }
    }

    epilogue(s0, 1);
}

// ---------------------------------------------------------------------------
// Combine (unchanged): xb[row][h*64+d] = (o0 + o1) / (l0 + l1).
// ---------------------------------------------------------------------------
__global__ __launch_bounds__(256) void combine(const float* __restrict__ po,
                                               const float* __restrict__ ls,
                                               bf16_t* __restrict__ xb) {
    const int idx = blockIdx.x * 256 + threadIdx.x;
    const int row = idx >> 8;
    const int c   = (idx & 255) * 4;
    const int h   = c >> 6;
    const int d   = c & 63;
    const size_t base0 = (size_t)(h) * S_LEN * DH + row * DH + d;
    const size_t base1 = (size_t)(NH + h) * S_LEN * DH + row * DH + d;
    float4 o0 = *(const float4*)(po + base0);
    float4 o1 = *(const float4*)(po + base1);
    float l = ls[(size_t)h * S_LEN + row] + ls[(size_t)(NH + h) * S_LEN + row];
    float inv = 1.0f / l;
    bf16x4 out;
    out[0] = (bf16_t)((o0.x + o1.x) * inv);
    out[1] = (bf16_t)((o0.y + o1.y) * inv);
    out[2] = (bf16_t)((o0.z + o1.z) * inv);
    out[3] = (bf16_t)((o0.w + o1.w) * inv);
    *(bf16x4*)(xb + (size_t)row * NE + c) = out;
}

// ---------------------------------------------------------------------------
// Projection (round-5 m32 version, unchanged): Y = X(bf16) @ W^T(bf16).
// ---------------------------------------------------------------------------
__global__ __launch_bounds__(256, 4) void proj(const bf16_t* __restrict__ xb,
                                               const bf16_t* __restrict__ wb,
                                               float* __restrict__ y) {
    __shared__ __align__(16) bf16_t wbuf[2][64 * 72];
    const int tid  = threadIdx.x;
    const int wave = tid >> 6;
    const int lane = tid & 63;
    const int l15  = lane & 15;
    const int quad = lane >> 4;
    const int m0 = blockIdx.x * 128 + wave * 32;   // wave owns 32 rows
    const int n0 = blockIdx.y * 64;

    const int row0 = tid >> 3;        // 0..31 (second chunk adds 32)
    const int tc8  = (tid & 7) * 8;

    f32x4 acc[2][4];
#pragma unroll
    for (int g = 0; g < 2; ++g)
#pragma unroll
        for (int nb = 0; nb < 4; ++nb) acc[g][nb] = (f32x4){0.f, 0.f, 0.f, 0.f};

    {
        bf16x8 wr0 = *(const bf16x8*)(wb + (n0 + row0) * NE + tc8);
        bf16x8 wr1 = *(const bf16x8*)(wb + (n0 + row0 + 32) * NE + tc8);
        *(bf16x8*)(wbuf[0] + row0 * 72 + tc8) = wr0;
        *(bf16x8*)(wbuf[0] + (row0 + 32) * 72 + tc8) = wr1;
    }
    bf16x8 a[2][2];
#pragma unroll
    for (int g = 0; g < 2; ++g)
#pragma unroll
        for (int kc = 0; kc < 2; ++kc)
            a[g][kc] = *(const bf16x8*)(xb + (m0 + g * 16 + l15) * NE + kc * 32 + quad * 8);
    __syncthreads();

    for (int kt = 0; kt < 16; ++kt) {
        const bf16_t* wb_ = wbuf[kt & 1];
        const bool pf = (kt + 1 < 16);
        bf16x8 wr0, wr1, an[2][2];
        if (pf) {
            const int kn = (kt + 1) * 64;
            wr0 = *(const bf16x8*)(wb + (n0 + row0) * NE + kn + tc8);
            wr1 = *(const bf16x8*)(wb + (n0 + row0 + 32) * NE + kn + tc8);
#pragma unroll
            for (int g = 0; g < 2; ++g)
#pragma unroll
                for (int kc = 0; kc < 2; ++kc)
                    an[g][kc] = *(const bf16x8*)(xb + (m0 + g * 16 + l15) * NE + kn + kc * 32 + quad * 8);
        }

#pragma unroll
        for (int nb = 0; nb < 4; ++nb)
#pragma unroll
            for (int kc = 0; kc < 2; ++kc) {
                bf16x8 b = *(const bf16x8*)(wb_ + (nb * 16 + l15) * 72 + kc * 32 + quad * 8);
#pragma unroll
                for (int g = 0; g < 2; ++g)
                    acc[g][nb] = __builtin_amdgcn_mfma_f32_16x16x32_bf16(a[g][kc], b, acc[g][nb], 0, 0, 0);
            }

        if (pf) {
            *(bf16x8*)(wbuf[(kt + 1) & 1] + row0 * 72 + tc8) = wr0;
            *(bf16x8*)(wbuf[(kt + 1) & 1] + (row0 + 32) * 72 + tc8) = wr1;
#pragma unroll
            for (int g = 0; g < 2; ++g)
#pragma unroll
                for (int kc = 0; kc < 2; ++kc) a[g][kc] = an[g][kc];
        }
        __syncthreads();
    }

#pragma unroll
    for (int g = 0; g < 2; ++g)
#pragma unroll
        for (int nb = 0; nb < 4; ++nb)
#pragma unroll
            for (int r = 0; r < 4; ++r)
                y[(m0 + g * 16 + quad * 4 + r) * NE + n0 + nb * 16 + l15] = acc[g][nb][r];
}

extern "C" void kernel_launch(void* const* d_in, const int* in_sizes, int n_in,
                              void* d_out, int out_size, void* d_ws, size_t ws_size,
                              hipStream_t stream) {
    const float* q = (const float*)d_in[0];
    const float* k = (const float*)d_in[1];
    const float* v = (const float*)d_in[2];
    const float* w = (const float*)d_in[3];
    float* y = (float*)d_out;

    // ws: bf16 {qb 4M | kb 4M | vt 4M | wb 1M | xb 4M} then fp32 {po 8M | ls 128K}
    bf16_t* ws = (bf16_t*)d_ws;
    bf16_t* qb = ws;
    bf16_t* kb = qb + 4 * 1024 * 1024;
    bf16_t* vt = kb + 4 * 1024 * 1024;
    bf16_t* wb = vt + 4 * 1024 * 1024;
    bf16_t* xb = wb + 1024 * 1024;
    float*  po = (float*)(xb + 4 * 1024 * 1024);
    float*  ls = po + (size_t)2 * NH * S_LEN * DH;

    pack_all<<<dim3(4096 + 1024), dim3(256), 0, stream>>>(q, k, w, v, qb, kb, wb, vt);
    attn<<<dim3(NH, 32), dim3(512), 0, stream>>>(qb, kb, vt, po, ls);
    combine<<<dim3(4096), dim3(256), 0, stream>>>(po, ls, xb);
    proj<<<dim3(S_LEN / 128, NE / 64), dim3(256), 0, stream>>>(xb, wb, y);
}

// Round 13
// 177.862 us; speedup vs baseline: 1.2910x; 1.0112x over previous
//
#include <hip/hip_runtime.h>

#define S_LEN 4096
#define NH 16
#define DH 64
#define NE 1024

typedef __bf16 bf16_t;
typedef __bf16 bf16x8 __attribute__((ext_vector_type(8)));
typedef __bf16 bf16x4 __attribute__((ext_vector_type(4)));
typedef __bf16 bf16x2 __attribute__((ext_vector_type(2)));
typedef float  f32x4  __attribute__((ext_vector_type(4)));

#define QSCALE 0.180336879f  // 0.125 * log2(e): softmax in exp2 domain

// ---------------------------------------------------------------------------
// Fused pack kernel (unchanged). Blocks [0,4096): q,k -> head-major bf16
// (q pre-scaled QSCALE) + W -> bf16. Blocks [4096,5120): V -> vt[h][d][t']
// transpose with the within-64 key permutation (vt[pos] = V[ip(pos)]) so
// attn's PV B-fragment is one contiguous b128. Lanes write CONTIGUOUS vt
// addresses, read inverse-permuted LDS entries.
// ---------------------------------------------------------------------------
__global__ __launch_bounds__(256) void pack_all(const float* __restrict__ q,
                                                const float* __restrict__ k,
                                                const float* __restrict__ w,
                                                const float* __restrict__ v,
                                                bf16_t* __restrict__ qb,
                                                bf16_t* __restrict__ kb,
                                                bf16_t* __restrict__ wb,
                                                bf16_t* __restrict__ vt) {
    __shared__ bf16_t tile[64][65];
    const int bid = blockIdx.x;
    if (bid < 4096) {
        const int tid = bid * 256 + threadIdx.x;
        const int e = tid * 4;
        const int s = e >> 10;
        const int c = e & (NE - 1);
        const int h = c >> 6;
        const int d = c & (DH - 1);
        const int o = (h * S_LEN + s) * DH + d;
        float4 qv = *(const float4*)(q + e);
        float4 kv = *(const float4*)(k + e);
        bf16x4 qo, ko;
        qo[0] = (bf16_t)(qv.x * QSCALE); qo[1] = (bf16_t)(qv.y * QSCALE);
        qo[2] = (bf16_t)(qv.z * QSCALE); qo[3] = (bf16_t)(qv.w * QSCALE);
        ko[0] = (bf16_t)kv.x; ko[1] = (bf16_t)kv.y; ko[2] = (bf16_t)kv.z; ko[3] = (bf16_t)kv.w;
        *(bf16x4*)(qb + o) = qo;
        *(bf16x4*)(kb + o) = ko;
        if (tid < (NE * NE / 4)) {
            float4 wv = *(const float4*)(w + tid * 4);
            bf16x4 wo;
            wo[0] = (bf16_t)wv.x; wo[1] = (bf16_t)wv.y; wo[2] = (bf16_t)wv.z; wo[3] = (bf16_t)wv.w;
            *(bf16x4*)(wb + tid * 4) = wo;
        }
    } else {
        const int vb = bid - 4096;
        const int h  = vb >> 6;
        const int t0 = (vb & 63) * 64;
        const int r  = threadIdx.x >> 6;   // 0..3
        const int cl = threadIdx.x & 63;
#pragma unroll
        for (int rep = 0; rep < 16; ++rep) {
            int i = rep * 4 + r;
            tile[cl][i] = (bf16_t)v[(t0 + i) * NE + h * DH + cl];
        }
        __syncthreads();
        const int r2  = threadIdx.x >> 5;        // 0..7
        const int cl2 = (threadIdx.x & 31) * 2;  // 0..62 even
        // inverse key permutation: old = n5*32 + n2*16 + n4*8 + n3*4 + n1n0
        const int ip = (cl2 & 32) + ((cl2 >> 2) & 1) * 16 + ((cl2 >> 4) & 1) * 8 +
                       ((cl2 >> 3) & 1) * 4 + (cl2 & 3);
#pragma unroll
        for (int rep = 0; rep < 8; ++rep) {
            int d = rep * 8 + r2;
            bf16x2 out;
            out[0] = tile[d][ip];
            out[1] = tile[d][ip + 1];
            *(bf16x2*)(vt + (h * DH + d) * S_LEN + t0 + cl2) = out;
        }
    }
}

// ---------------------------------------------------------------------------
// Flash attention v19 (round-12 verbatim, 63.9 us measured): 4-slot LDS
// ring (1 barrier / 2 tiles), swapped QK^T (no P round-trip), pre-permuted
// V (single b128 PV B-frags), ones-MFMA row sums, raw v_exp_f32 softmax
// (single-instruction exp2; libm expansion was the dominant VALU cost),
// hoisted per-chunk mask limit.
// ---------------------------------------------------------------------------
__global__ __launch_bounds__(512, 4) void attn(const bf16_t* __restrict__ qb,
                                               const bf16_t* __restrict__ kb,
                                               const bf16_t* __restrict__ vt,
                                               float* __restrict__ po,
                                               float* __restrict__ ls) {
    __shared__ __align__(16) bf16_t kbuf[4][64 * 72];
    __shared__ __align__(16) bf16_t vbuf[4][64 * 72];

    const int tid  = threadIdx.x;
    const int wave = tid >> 6;        // 0..7
    const int lane = tid & 63;
    const int l15  = lane & 15;
    const int quad = lane >> 4;
    const int h = blockIdx.x;
    const int x = blockIdx.y;

    const int sA = x;
    const int sB = 31 - x;
    const int n0 = x + 1;            // phase0 tile count
    const int b1 = sB + 1;           // phase1 first tile -> t0 base
    const int N  = 33;               // constant for all x

    const bf16_t* __restrict__ qh = qb + h * (S_LEN * DH);
    const bf16_t* __restrict__ kh = kb + h * (S_LEN * DH);
    const bf16_t* __restrict__ vh = vt + h * (DH * S_LEN);

    const int row0 = tid >> 3;        // 0..63
    const int tc8  = (tid & 7) * 8;   // 0..56
    const int stg  = row0 * 72 + tc8; // staging LDS offset (elements)
    const int frg  = l15 * 72 + quad * 8;  // fragment base offset (elements)

    f32x4 o_acc[4];
    f32x4 rs;                         // running row-sums via ones-MFMA
    bf16x8 qA[2];
    bf16x8 ones;
#pragma unroll
    for (int e = 0; e < 8; ++e) ones[e] = (bf16_t)1.0f;
    int s0 = sA * 128 + wave * 16;

    auto t0_of = [&](int j) { return (j < n0 ? j : b1 + (j - n0)) * 64; };

    auto load_q = [&](int s0_) {
#pragma unroll
        for (int dc = 0; dc < 2; ++dc)
            qA[dc] = *(const bf16x8*)(qh + (s0_ + l15) * DH + dc * 32 + quad * 8);
    };
    auto reset_acc = [&]() {
#pragma unroll
        for (int db = 0; db < 4; ++db) o_acc[db] = (f32x4){0.f, 0.f, 0.f, 0.f};
        rs = (f32x4){0.f, 0.f, 0.f, 0.f};
    };
    auto epilogue = [&](int s0_, int slot) {
        float* poz = po + (size_t)(slot * NH + h) * S_LEN * DH;
#pragma unroll
        for (int r = 0; r < 4; ++r)
#pragma unroll
            for (int db = 0; db < 4; ++db)
                poz[(s0_ + quad * 4 + r) * DH + db * 16 + l15] = o_acc[db][r];
        if (l15 == 0) {
            float* lsz = ls + (size_t)(slot * NH + h) * S_LEN;
#pragma unroll
            for (int r = 0; r < 4; ++r) lsz[s0_ + quad * 4 + r] = rs[r];
        }
    };

    load_q(s0);
    reset_acc();

    // prologue: stage tiles 0 and 1 into ring slots 0, 1
#pragma unroll
    for (int jj = 0; jj < 2; ++jj) {
        const int t0p = t0_of(jj);
        bf16x8 kr = *(const bf16x8*)(kh + (t0p + row0) * DH + tc8);
        bf16x8 vr = *(const bf16x8*)(vh + row0 * S_LEN + t0p + tc8);
        *(bf16x8*)(kbuf[jj] + stg) = kr;
        *(bf16x8*)(vbuf[jj] + stg) = vr;
    }
    __syncthreads();

    bf16x8 krn[2], vrn[2];            // prefetch regs for the next pair

#pragma unroll 2
    for (int j = 0; j < N; ++j) {
        if (j == n0) {  // phase switch (block-uniform)
            epilogue(s0, 0);
            s0 = sB * 128 + wave * 16;
            load_q(s0);
            reset_acc();
        }
        const int t0 = t0_of(j);
        const bf16_t* kb_ = kbuf[j & 3];
        const bf16_t* vb_ = vbuf[j & 3];

        if ((j & 1) == 0) {
            // pair start: issue global loads for tiles j+2, j+3 (uniform guards)
#pragma unroll
            for (int u = 0; u < 2; ++u) {
                const int jn = j + 2 + u;
                if (jn < N) {
                    const int tn = t0_of(jn);
                    krn[u] = *(const bf16x8*)(kh + (tn + row0) * DH + tc8);
                    vrn[u] = *(const bf16x8*)(vh + row0 * S_LEN + tn + tc8);
                }
            }
        }

        // wave-uniform: this tile contributes only if some key <= some query
        if (t0 <= s0 + 15) {
            // ---- swapped QK^T: A = K fragments, B = Q (in registers)
            f32x4 c_[4];
#pragma unroll
            for (int ch = 0; ch < 4; ++ch) {
                bf16x8 kB0 = *(const bf16x8*)(kb_ + frg + ch * (16 * 72));
                bf16x8 kB1 = *(const bf16x8*)(kb_ + frg + ch * (16 * 72) + 32);
                f32x4 zr = (f32x4){0.f, 0.f, 0.f, 0.f};
                zr = __builtin_amdgcn_mfma_f32_16x16x32_bf16(kB0, qA[0], zr, 0, 0, 0);
                zr = __builtin_amdgcn_mfma_f32_16x16x32_bf16(kB1, qA[1], zr, 0, 0, 0);
                c_[ch] = zr;
            }

            // ---- mask + exp2 + lane-local pack into PV A-fragments
            // lane holds S^T[key=t0+16ch+4quad+r][query=s0+l15].
            // Mask limit hoisted: element (ch,r) masked iff r > lim(ch).
            const int query = s0 + l15;
            float p[4][4];
#pragma unroll
            for (int ch = 0; ch < 4; ++ch) {
                if (t0 + ch * 16 <= s0 + 15) {       // wave-uniform chunk-live
                    const bool edge = (t0 + ch * 16 + 15 > s0);
                    const int lim = query - (t0 + ch * 16 + quad * 4);
#pragma unroll
                    for (int r = 0; r < 4; ++r) {
                        float cc = c_[ch][r];
                        if (edge && r > lim) cc = -INFINITY;
                        p[ch][r] = __builtin_amdgcn_exp2f(cc);
                    }
                } else {
#pragma unroll
                    for (int r = 0; r < 4; ++r) p[ch][r] = 0.0f;
                }
            }

            bf16x8 pA[2];
#pragma unroll
            for (int kc = 0; kc < 2; ++kc) {
                bf16x8 t;
                t[0] = (bf16_t)p[2 * kc][0];     t[1] = (bf16_t)p[2 * kc][1];
                t[2] = (bf16_t)p[2 * kc][2];     t[3] = (bf16_t)p[2 * kc][3];
                t[4] = (bf16_t)p[2 * kc + 1][0]; t[5] = (bf16_t)p[2 * kc + 1][1];
                t[6] = (bf16_t)p[2 * kc + 1][2]; t[7] = (bf16_t)p[2 * kc + 1][3];
                pA[kc] = t;
            }

            // ---- row-sums on the matrix pipe (replaces 16 VALU adds)
            rs = __builtin_amdgcn_mfma_f32_16x16x32_bf16(pA[0], ones, rs, 0, 0, 0);
            rs = __builtin_amdgcn_mfma_f32_16x16x32_bf16(pA[1], ones, rs, 0, 0, 0);

            // ---- PV: V pre-permuted -> single uniform b128 per fragment
#pragma unroll
            for (int db = 0; db < 4; ++db) {
#pragma unroll
                for (int kc = 0; kc < 2; ++kc) {
                    bf16x8 vB = *(const bf16x8*)(vb_ + frg + db * (16 * 72) + kc * 32);
                    o_acc[db] = __builtin_amdgcn_mfma_f32_16x16x32_bf16(pA[kc], vB, o_acc[db], 0, 0, 0);
                }
            }
        }

        if (j & 1) {
            // pair end: commit staged tiles j+1, j+2 to their ring slots,
            // then ONE barrier for the pair.
#pragma unroll
            for (int u = 0; u < 2; ++u) {
                const int jn = j + 1 + u;
                if (jn < N) {
                    *(bf16x8*)(kbuf[jn & 3] + stg) = krn[u];
                    *(bf16x8*)(vbuf[jn & 3] + stg) = vrn[u];
                }
            }
            __syncthreads();
        }
    }

    epilogue(s0, 1);
}

// ---------------------------------------------------------------------------
// Combine (unchanged): xb[row][h*64+d] = (o0 + o1) / (l0 + l1).
// ---------------------------------------------------------------------------
__global__ __launch_bounds__(256) void combine(const float* __restrict__ po,
                                               const float* __restrict__ ls,
                                               bf16_t* __restrict__ xb) {
    const int idx = blockIdx.x * 256 + threadIdx.x;
    const int row = idx >> 8;
    const int c   = (idx & 255) * 4;
    const int h   = c >> 6;
    const int d   = c & 63;
    const size_t base0 = (size_t)(h) * S_LEN * DH + row * DH + d;
    const size_t base1 = (size_t)(NH + h) * S_LEN * DH + row * DH + d;
    float4 o0 = *(const float4*)(po + base0);
    float4 o1 = *(const float4*)(po + base1);
    float l = ls[(size_t)h * S_LEN + row] + ls[(size_t)(NH + h) * S_LEN + row];
    float inv = 1.0f / l;
    bf16x4 out;
    out[0] = (bf16_t)((o0.x + o1.x) * inv);
    out[1] = (bf16_t)((o0.y + o1.y) * inv);
    out[2] = (bf16_t)((o0.z + o1.z) * inv);
    out[3] = (bf16_t)((o0.w + o1.w) * inv);
    *(bf16x4*)(xb + (size_t)row * NE + c) = out;
}

// ---------------------------------------------------------------------------
// Projection v10: Y[4096][1024] = X(bf16) @ W^T(bf16), fp32 out.
// CANONICAL both-staged GEMM: the scattered per-wave A-fragment global
// loads (lane = row at 2KB stride -> 16 cache lines per b128) were proj's
// suspected binding constraint (explains the round-5 m32 null: B-savings
// cancelled by doubled A-scatter). Now the A-panel (128x64/chunk) and
// W-panel (64x64/chunk) are both staged via fully-coalesced 128B global
// runs and read back as the stride-72 ds_read_b128 pattern proven 2-way-
// free everywhere else. 512 threads = 8 waves x m16; BM=128 BN=64; grid
// (32,16) = 512 blocks; LDS 55296B -> 2 blocks/CU = 16 waves/CU (same
// occupancy as v9). Double-buffered, one sync per chunk. MFMA algebra and
// output indexing identical to the passing v9.
// ---------------------------------------------------------------------------
__global__ __launch_bounds__(512, 2) void proj(const bf16_t* __restrict__ xb,
                                               const bf16_t* __restrict__ wb,
                                               float* __restrict__ y) {
    __shared__ __align__(16) bf16_t abuf[2][128 * 72];
    __shared__ __align__(16) bf16_t wbuf[2][64 * 72];
    const int tid  = threadIdx.x;
    const int wave = tid >> 6;        // 0..7
    const int lane = tid & 63;
    const int l15  = lane & 15;
    const int quad = lane >> 4;
    const int mb = blockIdx.x * 128;  // block row base
    const int m0 = mb + wave * 16;    // wave owns 16 rows
    const int n0 = blockIdx.y * 64;

    // A staging: 1024 slots of 8 elts; thread covers slots tid, tid+512
    const int rowA0 = tid >> 3;            // 0..63   (slot = tid)
    const int rowA1 = (tid + 512) >> 3;    // 64..127 (slot = tid+512)
    const int colA  = (tid & 7) * 8;
    // W staging: 512 slots, one per thread
    const int rowW  = tid >> 3;            // 0..63
    const int frg   = l15 * 72 + quad * 8; // fragment base (elements)

    f32x4 acc[4];
#pragma unroll
    for (int nb = 0; nb < 4; ++nb) acc[nb] = (f32x4){0.f, 0.f, 0.f, 0.f};

    // prologue: stage chunk 0
    {
        bf16x8 a0 = *(const bf16x8*)(xb + (mb + rowA0) * NE + colA);
        bf16x8 a1 = *(const bf16x8*)(xb + (mb + rowA1) * NE + colA);
        bf16x8 w0 = *(const bf16x8*)(wb + (n0 + rowW) * NE + colA);
        *(bf16x8*)(abuf[0] + rowA0 * 72 + colA) = a0;
        *(bf16x8*)(abuf[0] + rowA1 * 72 + colA) = a1;
        *(bf16x8*)(wbuf[0] + rowW * 72 + colA) = w0;
    }
    __syncthreads();

    for (int kt = 0; kt < 16; ++kt) {
        const bf16_t* ab_ = abuf[kt & 1];
        const bf16_t* wb_ = wbuf[kt & 1];
        const bool pf = (kt + 1 < 16);
        bf16x8 an0, an1, wn;
        if (pf) {
            const int kn = (kt + 1) * 64;
            an0 = *(const bf16x8*)(xb + (mb + rowA0) * NE + kn + colA);
            an1 = *(const bf16x8*)(xb + (mb + rowA1) * NE + kn + colA);
            wn  = *(const bf16x8*)(wb + (n0 + rowW) * NE + kn + colA);
        }

        bf16x8 a0 = *(const bf16x8*)(ab_ + wave * (16 * 72) + frg);
        bf16x8 a1 = *(const bf16x8*)(ab_ + wave * (16 * 72) + frg + 32);
#pragma unroll
        for (int nb = 0; nb < 4; ++nb) {
            bf16x8 b0 = *(const bf16x8*)(wb_ + nb * (16 * 72) + frg);
            bf16x8 b1 = *(const bf16x8*)(wb_ + nb * (16 * 72) + frg + 32);
            acc[nb] = __builtin_amdgcn_mfma_f32_16x16x32_bf16(a0, b0, acc[nb], 0, 0, 0);
            acc[nb] = __builtin_amdgcn_mfma_f32_16x16x32_bf16(a1, b1, acc[nb], 0, 0, 0);
        }

        if (pf) {
            bf16_t* ad = abuf[(kt + 1) & 1];
            bf16_t* wd = wbuf[(kt + 1) & 1];
            *(bf16x8*)(ad + rowA0 * 72 + colA) = an0;
            *(bf16x8*)(ad + rowA1 * 72 + colA) = an1;
            *(bf16x8*)(wd + rowW * 72 + colA) = wn;
        }
        __syncthreads();
    }

#pragma unroll
    for (int nb = 0; nb < 4; ++nb)
#pragma unroll
        for (int r = 0; r < 4; ++r)
            y[(m0 + quad * 4 + r) * NE + n0 + nb * 16 + l15] = acc[nb][r];
}

extern "C" void kernel_launch(void* const* d_in, const int* in_sizes, int n_in,
                              void* d_out, int out_size, void* d_ws, size_t ws_size,
                              hipStream_t stream) {
    const float* q = (const float*)d_in[0];
    const float* k = (const float*)d_in[1];
    const float* v = (const float*)d_in[2];
    const float* w = (const float*)d_in[3];
    float* y = (float*)d_out;

    // ws: bf16 {qb 4M | kb 4M | vt 4M | wb 1M | xb 4M} then fp32 {po 8M | ls 128K}
    bf16_t* ws = (bf16_t*)d_ws;
    bf16_t* qb = ws;
    bf16_t* kb = qb + 4 * 1024 * 1024;
    bf16_t* vt = kb + 4 * 1024 * 1024;
    bf16_t* wb = vt + 4 * 1024 * 1024;
    bf16_t* xb = wb + 1024 * 1024;
    float*  po = (float*)(xb + 4 * 1024 * 1024);
    float*  ls = po + (size_t)2 * NH * S_LEN * DH;

    pack_all<<<dim3(4096 + 1024), dim3(256), 0, stream>>>(q, k, w, v, qb, kb, wb, vt);
    attn<<<dim3(NH, 32), dim3(512), 0, stream>>>(qb, kb, vt, po, ls);
    combine<<<dim3(4096), dim3(256), 0, stream>>>(po, ls, xb);
    proj<<<dim3(S_LEN / 128, NE / 64), dim3(512), 0, stream>>>(xb, wb, y);
}